// Round 8
// baseline (384.038 us; speedup 1.0000x reference)
//
#include <hip/hip_runtime.h>
#include <math.h>

#define NN    8192
#define KF    512
#define DF    64
#define NCH   32
#define NCOL  130
#define KSPLIT 4
#define REPS  10   // instrumentation: amplify each kernel 10x (idempotent bodies)

typedef __attribute__((ext_vector_type(8))) short bf16x8;
typedef __attribute__((ext_vector_type(4))) float f32x4;

__device__ __forceinline__ unsigned short f2bf_rn(float f) {
    unsigned u = __float_as_uint(f);
    unsigned r = (u + 0x7fffu + ((u >> 16) & 1u)) >> 16;
    return (unsigned short)r;
}
__device__ __forceinline__ float bf2f(unsigned short s) {
    return __uint_as_float(((unsigned)s) << 16);
}

// ======== K0: v2 = W^T w2; Wh/Wl = split-bf16 of W ========
__global__ __launch_bounds__(256) void k_prep(const float* __restrict__ W,
        const float* __restrict__ w2, float* __restrict__ v2,
        unsigned short* __restrict__ Wh, unsigned short* __restrict__ Wl) {
    for (int rep = 0; rep < REPS; ++rep) {
        const int k = blockIdx.x * 256 + threadIdx.x;
        float a2 = 0.f;
        for (int o = 0; o < DF; ++o) {
            const float wv = W[(size_t)o * KF + k];
            a2 = fmaf(wv, w2[o], a2);
            const unsigned short hi = f2bf_rn(wv);
            Wh[(size_t)o * KF + k] = hi;
            Wl[(size_t)o * KF + k] = f2bf_rn(wv - bf2f(hi));
        }
        v2[k] = a2;
        __syncthreads();
        asm volatile("" ::: "memory");
    }
}

// ======== K1: hpart[ks] = x @ W^T via split-bf16 MFMA ========
__global__ __launch_bounds__(256) void k_gemm(const float* __restrict__ x,
        const unsigned short* __restrict__ Wh, const unsigned short* __restrict__ Wl,
        float* __restrict__ hpart) {
    __shared__ unsigned short xh[64][136];
    __shared__ unsigned short xl[64][136];
    for (int rep = 0; rep < REPS; ++rep) {
        const int tid = threadIdx.x;
        const int rb = blockIdx.x & 127, ks = blockIdx.x >> 7;
        const int row0 = rb * 64, kbase = ks * (KF / KSPLIT);
        {
            const int r = tid >> 2, q = tid & 3;
            const float* xr = x + (size_t)(row0 + r) * KF + kbase + q * 32;
            #pragma unroll
            for (int i = 0; i < 8; ++i) {
                const float4 v = *reinterpret_cast<const float4*>(xr + i * 4);
                ushort4 h, l;
                h.x = f2bf_rn(v.x); l.x = f2bf_rn(v.x - bf2f(h.x));
                h.y = f2bf_rn(v.y); l.y = f2bf_rn(v.y - bf2f(h.y));
                h.z = f2bf_rn(v.z); l.z = f2bf_rn(v.z - bf2f(h.z));
                h.w = f2bf_rn(v.w); l.w = f2bf_rn(v.w - bf2f(h.w));
                *reinterpret_cast<ushort4*>(&xh[r][q * 32 + i * 4]) = h;
                *reinterpret_cast<ushort4*>(&xl[r][q * 32 + i * 4]) = l;
            }
        }
        __syncthreads();
        const int w = tid >> 6, l = tid & 63;
        const int fr = l & 15, fq = l >> 4;
        f32x4 acc[4] = {{0.f,0.f,0.f,0.f},{0.f,0.f,0.f,0.f},{0.f,0.f,0.f,0.f},{0.f,0.f,0.f,0.f}};
        #pragma unroll
        for (int kstep = 0; kstep < 4; ++kstep) {
            const int k0 = kstep * 32;
            const bf16x8 ah = *reinterpret_cast<const bf16x8*>(&xh[w * 16 + fr][k0 + fq * 8]);
            const bf16x8 al = *reinterpret_cast<const bf16x8*>(&xl[w * 16 + fr][k0 + fq * 8]);
            #pragma unroll
            for (int cg = 0; cg < 4; ++cg) {
                const size_t wb = (size_t)(cg * 16 + fr) * KF + kbase + k0 + fq * 8;
                const bf16x8 bh = *reinterpret_cast<const bf16x8*>(Wh + wb);
                const bf16x8 bl = *reinterpret_cast<const bf16x8*>(Wl + wb);
                acc[cg] = __builtin_amdgcn_mfma_f32_16x16x32_bf16(ah, bh, acc[cg], 0, 0, 0);
                acc[cg] = __builtin_amdgcn_mfma_f32_16x16x32_bf16(al, bh, acc[cg], 0, 0, 0);
                acc[cg] = __builtin_amdgcn_mfma_f32_16x16x32_bf16(ah, bl, acc[cg], 0, 0, 0);
            }
        }
        float* hp = hpart + (size_t)ks * NN * DF;
        #pragma unroll
        for (int cg = 0; cg < 4; ++cg)
            #pragma unroll
            for (int j = 0; j < 4; ++j)
                hp[(size_t)(row0 + w * 16 + fq * 4 + j) * DF + cg * 16 + fr] = acc[cg][j];
        __syncthreads();
        asm volatile("" ::: "memory");
    }
}

// ======== K1b: h1 = sum_s hpart[s]; s1 = h1 @ w_att1 ========
__global__ __launch_bounds__(256) void k_combine(const float* __restrict__ hpart,
        const float* __restrict__ w_att1, float* __restrict__ h1, float* __restrict__ s1) {
    for (int rep = 0; rep < REPS; ++rep) {
        const int lane = threadIdx.x & 63, wave = threadIdx.x >> 6;
        const int row = blockIdx.x * 4 + wave;
        float v = 0.f;
        #pragma unroll
        for (int s = 0; s < KSPLIT; ++s) v += hpart[((size_t)s * NN + row) * DF + lane];
        h1[(size_t)row * DF + lane] = v;
        float p = v * w_att1[lane];
        #pragma unroll
        for (int off = 32; off; off >>= 1) p += __shfl_xor(p, off);
        if (lane == 0) s1[row] = p;
        __syncthreads();
        asm volatile("" ::: "memory");
    }
}

// ======== K2: s2 = n @ v2 ========
__global__ __launch_bounds__(256) void k_s2(const float* __restrict__ n,
        const float* __restrict__ v2, float* __restrict__ s2) {
    for (int rep = 0; rep < REPS; ++rep) {
        const int lane = threadIdx.x & 63;
        const int row = (blockIdx.x * 256 + threadIdx.x) >> 6;
        const float4* a = reinterpret_cast<const float4*>(n + (size_t)row * KF);
        const float4* b = reinterpret_cast<const float4*>(v2);
        float acc = 0.f;
        #pragma unroll
        for (int c = 0; c < 2; ++c) {
            float4 av = a[lane + c * 64], bv = b[lane + c * 64];
            acc = fmaf(av.x, bv.x, fmaf(av.y, bv.y, fmaf(av.z, bv.z, fmaf(av.w, bv.w, acc))));
        }
        #pragma unroll
        for (int off = 32; off; off >>= 1) acc += __shfl_xor(acc, off);
        if (lane == 0) s2[row] = acc;
        __syncthreads();
        asm volatile("" ::: "memory");
    }
}

// ======== K3: brute-force rank partial counts ========
__global__ __launch_bounds__(256) void k_count(const float* __restrict__ s2,
                                               int* __restrict__ partial) {
    __shared__ float sk[256];
    for (int rep = 0; rep < REPS; ++rep) {
        const int j = blockIdx.x * 256 + threadIdx.x;
        const int k0 = blockIdx.y * 256;
        sk[threadIdx.x] = s2[k0 + threadIdx.x];
        __syncthreads();
        const float mine = s2[j];
        int cnt = 0;
        #pragma unroll 8
        for (int t = 0; t < 256; ++t) {
            float v = sk[t];
            int idx = k0 + t;
            cnt += (v < mine) || (v == mine && idx < j);
        }
        partial[(size_t)blockIdx.y * NN + j] = cnt;
        __syncthreads();
        asm volatile("" ::: "memory");
    }
}

// ======== K4: reduce ranks + scatter ========
__global__ __launch_bounds__(256) void k_scatter(const float* __restrict__ s2,
        const int* __restrict__ partial, int* __restrict__ order,
        float* __restrict__ s2s, double* __restrict__ wpos, double* __restrict__ wneg) {
    for (int rep = 0; rep < REPS; ++rep) {
        const int j = blockIdx.x * 256 + threadIdx.x;
        int r = 0;
        for (int kb = 0; kb < NCH; ++kb) r += partial[(size_t)kb * NN + j];
        const float v = s2[j];
        order[r] = j;
        s2s[r] = v;
        wpos[r] = exp((double)v);
        wneg[r] = exp(0.2 * (double)v);
        __syncthreads();
        asm volatile("" ::: "memory");
    }
}

// ======== K5: per-chunk totals ========
__global__ __launch_bounds__(256) void k_chunksum(const float* __restrict__ h1,
        const int* __restrict__ order, const double* __restrict__ wpos,
        const double* __restrict__ wneg, double* __restrict__ cT) {
    __shared__ double red[256];
    for (int rep = 0; rep < REPS; ++rep) {
        const int col = blockIdx.x >> 5, c = blockIdx.x & 31;
        const int p = c * 256 + threadIdx.x;
        const double wgt = (col < 65) ? wpos[p] : wneg[p];
        const int d = (col < 65) ? col : col - 65;
        double val = (d < DF) ? wgt * (double)h1[(size_t)order[p] * DF + d] : wgt;
        red[threadIdx.x] = val;
        __syncthreads();
        for (int s = 128; s; s >>= 1) {
            if (threadIdx.x < s) red[threadIdx.x] += red[threadIdx.x + s];
            __syncthreads();
        }
        if (threadIdx.x == 0) cT[blockIdx.x] = red[0];
        __syncthreads();
        asm volatile("" ::: "memory");
    }
}

// ======== K6: chunk-total scan ========
__global__ void k_chunkscan(const double* __restrict__ cT, double* __restrict__ cO,
                            double* __restrict__ E) {
    for (int rep = 0; rep < REPS; ++rep) {
        const int col = threadIdx.x;
        if (col < NCOL) {
            double run = 0.0;
            for (int c = 0; c < NCH; ++c) {
                cO[(size_t)col * NCH + c] = run;
                run += cT[(size_t)col * NCH + c];
            }
            E[(size_t)NN * NCOL + col] = run;
        }
        __syncthreads();
        asm volatile("" ::: "memory");
    }
}

// ======== K7: per-chunk exclusive scan -> E ========
__global__ __launch_bounds__(256) void k_scan(const float* __restrict__ h1,
        const int* __restrict__ order, const double* __restrict__ wpos,
        const double* __restrict__ wneg, const double* __restrict__ cO,
        double* __restrict__ E) {
    __shared__ double buf[2][256];
    for (int rep = 0; rep < REPS; ++rep) {
        const int col = blockIdx.x >> 5, c = blockIdx.x & 31;
        const int tid = threadIdx.x;
        const int p = c * 256 + tid;
        const double wgt = (col < 65) ? wpos[p] : wneg[p];
        const int d = (col < 65) ? col : col - 65;
        double val = (d < DF) ? wgt * (double)h1[(size_t)order[p] * DF + d] : wgt;
        buf[0][tid] = val;
        int cur = 0;
        for (int off = 1; off < 256; off <<= 1) {
            __syncthreads();
            double t = buf[cur][tid];
            if (tid >= off) t += buf[cur][tid - off];
            buf[cur ^ 1][tid] = t;
            cur ^= 1;
        }
        __syncthreads();
        const double excl = tid ? buf[cur][tid - 1] : 0.0;
        E[(size_t)p * NCOL + col] = cO[blockIdx.x] + excl;
        __syncthreads();
        asm volatile("" ::: "memory");
    }
}

// ======== K8: per-row binary search + combine ========
__global__ __launch_bounds__(256) void k_out(const float* __restrict__ s1,
        const float* __restrict__ s2s, const double* __restrict__ E,
        float* __restrict__ out) {
    for (int rep = 0; rep < REPS; ++rep) {
        const int lane = threadIdx.x & 63, wave = threadIdx.x >> 6;
        const int i = blockIdx.x * 4 + wave;
        const float s1v = s1[i];
        const float t = -s1v;
        int lo = 0, hi = NN;
        while (lo < hi) {
            int mid = (lo + hi) >> 1;
            if (s2s[mid] < t) lo = mid + 1; else hi = mid;
        }
        const double* Ek = E + (size_t)lo * NCOL;
        const double* Et = E + (size_t)NN * NCOL;
        const double e1 = exp((double)s1v);
        const double e2 = exp(0.2 * (double)s1v);
        const double num = e1 * (Et[lane] - Ek[lane]) + e2 * Ek[65 + lane];
        const double den = e1 * (Et[DF] - Ek[DF]) + e2 * Ek[65 + DF];
        out[(size_t)i * DF + lane] = (float)(num / den);
        __syncthreads();
        asm volatile("" ::: "memory");
    }
}

extern "C" void kernel_launch(void* const* d_in, const int* in_sizes, int n_in,
                              void* d_out, int out_size, void* d_ws, size_t ws_size,
                              hipStream_t stream) {
    const float* x    = (const float*)d_in[0];
    const float* nmat = (const float*)d_in[1];
    const float* W    = (const float*)d_in[2];
    const float* w1   = (const float*)d_in[3];
    const float* w2   = (const float*)d_in[4];
    float* out = (float*)d_out;

    char* ws = (char*)d_ws;
    size_t off = 0;
    auto alloc = [&](size_t bytes) -> void* {
        void* p = ws + off;
        off += (bytes + 255) & ~(size_t)255;
        return p;
    };
    unsigned short* Wh = (unsigned short*)alloc((size_t)DF * KF * 2);
    unsigned short* Wl = (unsigned short*)alloc((size_t)DF * KF * 2);
    float*  v2      = (float*)alloc((size_t)KF * 4);
    float*  h1      = (float*)alloc((size_t)NN * DF * 4);
    float*  s1      = (float*)alloc((size_t)NN * 4);
    float*  s2      = (float*)alloc((size_t)NN * 4);
    int*    partial = (int*)alloc((size_t)NCH * NN * 4);
    int*    order   = (int*)alloc((size_t)NN * 4);
    float*  s2s     = (float*)alloc((size_t)NN * 4);
    double* wpos    = (double*)alloc((size_t)NN * 8);
    double* wneg    = (double*)alloc((size_t)NN * 8);
    double* cT      = (double*)alloc((size_t)NCOL * NCH * 8);
    double* cO      = (double*)alloc((size_t)NCOL * NCH * 8);
    double* E       = (double*)alloc((size_t)(NN + 1) * NCOL * 8);
    float*  hpart   = (float*)E;   // alias, liveness disjoint (see R7 note)

    k_prep<<<2, 256, 0, stream>>>(W, w2, v2, Wh, Wl);
    k_gemm<<<512, 256, 0, stream>>>(x, Wh, Wl, hpart);
    k_combine<<<NN / 4, 256, 0, stream>>>(hpart, w1, h1, s1);
    k_s2<<<NN / 4, 256, 0, stream>>>(nmat, v2, s2);
    k_count<<<dim3(NCH, NCH), 256, 0, stream>>>(s2, partial);
    k_scatter<<<NCH, 256, 0, stream>>>(s2, partial, order, s2s, wpos, wneg);
    k_chunksum<<<NCOL * NCH, 256, 0, stream>>>(h1, order, wpos, wneg, cT);
    k_chunkscan<<<1, 256, 0, stream>>>(cT, cO, E);
    k_scan<<<NCOL * NCH, 256, 0, stream>>>(h1, order, wpos, wneg, cO, E);
    k_out<<<NN / 4, 256, 0, stream>>>(s1, s2s, E, out);
}

// Round 9
// 78.758 us; speedup vs baseline: 4.8762x; 4.8762x over previous
//
#include <hip/hip_runtime.h>
#include <math.h>

#define NN    8192
#define KF    512
#define DF    64
#define NCH   32
#define EC    136   // E row: [posH 0..63][negH 64..127][onesP 128][onesN 129][pad]

typedef __attribute__((ext_vector_type(8))) short bf16x8;
typedef __attribute__((ext_vector_type(8))) unsigned short ushort8;
typedef __attribute__((ext_vector_type(4))) float f32x4;

__device__ __forceinline__ unsigned short f2bf_rn(float f) {
    unsigned u = __float_as_uint(f);
    unsigned r = (u + 0x7fffu + ((u >> 16) & 1u)) >> 16;
    return (unsigned short)r;
}
__device__ __forceinline__ float bf2f(unsigned short s) {
    return __uint_as_float(((unsigned)s) << 16);
}

// ======== K0: v2 = W^T w2; Wh/Wl = split-bf16 of W (R7-proven) ========
__global__ __launch_bounds__(256) void k_prep(const float* __restrict__ W,
        const float* __restrict__ w2, float* __restrict__ v2,
        unsigned short* __restrict__ Wh, unsigned short* __restrict__ Wl) {
    const int k = blockIdx.x * 256 + threadIdx.x;
    float a2 = 0.f;
    for (int o = 0; o < DF; ++o) {
        const float wv = W[(size_t)o * KF + k];
        a2 = fmaf(wv, w2[o], a2);
        const unsigned short hi = f2bf_rn(wv);
        Wh[(size_t)o * KF + k] = hi;
        Wl[(size_t)o * KF + k] = f2bf_rn(wv - bf2f(hi));
    }
    v2[k] = a2;
}

// ======== K1: blocks 0..511:  h1 = x@W^T (16 rows, full-K MFMA) + s1 fused
// ========     blocks 512..767: s2 = n@v2, 32 rows each
__global__ __launch_bounds__(256) void k_main(const float* __restrict__ x,
        const float* __restrict__ nmat,
        const unsigned short* __restrict__ Wh, const unsigned short* __restrict__ Wl,
        const float* __restrict__ v2, const float* __restrict__ w1,
        float* __restrict__ h1, float* __restrict__ s1, float* __restrict__ s2) {
    __shared__ unsigned short xh[16][520];   // 16.6 KB (520 = 512 + 8 pad, 16B-aligned rows)
    __shared__ unsigned short xl[16][520];   // 16.6 KB
    __shared__ float s1buf[16][4];
    const int tid = threadIdx.x;
    const int bid = blockIdx.x;
    if (bid < 512) {
        const int row0 = bid * 16;
        // ---- stage 16 rows x 512 k as bf16 hi/lo
        {
            const int r = tid >> 4, q = tid & 15;   // 16 rows x 32-col chunks
            const float* xr = x + (size_t)(row0 + r) * KF + q * 32;
            #pragma unroll
            for (int i2 = 0; i2 < 4; ++i2) {
                const float4 va = *reinterpret_cast<const float4*>(xr + i2 * 8);
                const float4 vb = *reinterpret_cast<const float4*>(xr + i2 * 8 + 4);
                ushort8 h, l;
                h[0]=f2bf_rn(va.x); l[0]=f2bf_rn(va.x-bf2f(h[0]));
                h[1]=f2bf_rn(va.y); l[1]=f2bf_rn(va.y-bf2f(h[1]));
                h[2]=f2bf_rn(va.z); l[2]=f2bf_rn(va.z-bf2f(h[2]));
                h[3]=f2bf_rn(va.w); l[3]=f2bf_rn(va.w-bf2f(h[3]));
                h[4]=f2bf_rn(vb.x); l[4]=f2bf_rn(vb.x-bf2f(h[4]));
                h[5]=f2bf_rn(vb.y); l[5]=f2bf_rn(vb.y-bf2f(h[5]));
                h[6]=f2bf_rn(vb.z); l[6]=f2bf_rn(vb.z-bf2f(h[6]));
                h[7]=f2bf_rn(vb.w); l[7]=f2bf_rn(vb.w-bf2f(h[7]));
                *reinterpret_cast<ushort8*>(&xh[r][q * 32 + i2 * 8]) = h;
                *reinterpret_cast<ushort8*>(&xl[r][q * 32 + i2 * 8]) = l;
            }
        }
        __syncthreads();
        // ---- MFMA: wave w owns col-group cg=w (16 cols); all waves share the 16 rows
        const int w = tid >> 6, l = tid & 63;
        const int fr = l & 15, fq = l >> 4;
        f32x4 acc = {0.f, 0.f, 0.f, 0.f};
        const size_t wrow = (size_t)(w * 16 + fr) * KF;
        #pragma unroll 4
        for (int ks = 0; ks < 16; ++ks) {
            const int k0 = ks * 32;
            const bf16x8 ah = *reinterpret_cast<const bf16x8*>(&xh[fr][k0 + fq * 8]);
            const bf16x8 al = *reinterpret_cast<const bf16x8*>(&xl[fr][k0 + fq * 8]);
            const bf16x8 bh = *reinterpret_cast<const bf16x8*>(Wh + wrow + k0 + fq * 8);
            const bf16x8 bl = *reinterpret_cast<const bf16x8*>(Wl + wrow + k0 + fq * 8);
            acc = __builtin_amdgcn_mfma_f32_16x16x32_bf16(ah, bh, acc, 0, 0, 0);
            acc = __builtin_amdgcn_mfma_f32_16x16x32_bf16(al, bh, acc, 0, 0, 0);
            acc = __builtin_amdgcn_mfma_f32_16x16x32_bf16(ah, bl, acc, 0, 0, 0);
        }
        // ---- h1 store (D: col = w*16+fr, row = fq*4+j) + fused s1 partial
        const float w1v = w1[w * 16 + fr];
        #pragma unroll
        for (int j = 0; j < 4; ++j) {
            const int row = row0 + fq * 4 + j;
            h1[(size_t)row * DF + w * 16 + fr] = acc[j];
            float p = acc[j] * w1v;
            p += __shfl_xor(p, 1); p += __shfl_xor(p, 2);
            p += __shfl_xor(p, 4); p += __shfl_xor(p, 8);
            if (fr == 0) s1buf[fq * 4 + j][w] = p;
        }
        __syncthreads();
        if (tid < 16)
            s1[row0 + tid] = s1buf[tid][0] + s1buf[tid][1] + s1buf[tid][2] + s1buf[tid][3];
    } else {
        // ---- s2 path (R2-proven): stage v2, one wave per row, 32 rows
        float* v2s = reinterpret_cast<float*>(&xh[0][0]);
        v2s[tid] = v2[tid]; v2s[tid + 256] = v2[tid + 256];
        __syncthreads();
        const int lane = tid & 63, w = tid >> 6;
        const float4 b0 = *reinterpret_cast<const float4*>(&v2s[lane * 4]);
        const float4 b1 = *reinterpret_cast<const float4*>(&v2s[256 + lane * 4]);
        const int row0 = (bid - 512) * 32;
        for (int rr = 0; rr < 8; ++rr) {
            const int row = row0 + w * 8 + rr;
            const float4 n0 = *reinterpret_cast<const float4*>(nmat + (size_t)row * KF + lane * 4);
            const float4 n1 = *reinterpret_cast<const float4*>(nmat + (size_t)row * KF + 256 + lane * 4);
            float acc = n0.x * b0.x;
            acc = fmaf(n0.y, b0.y, acc); acc = fmaf(n0.z, b0.z, acc); acc = fmaf(n0.w, b0.w, acc);
            acc = fmaf(n1.x, b1.x, acc); acc = fmaf(n1.y, b1.y, acc);
            acc = fmaf(n1.z, b1.z, acc); acc = fmaf(n1.w, b1.w, acc);
            #pragma unroll
            for (int off = 32; off; off >>= 1) acc += __shfl_xor(acc, off);
            if (lane == 0) s2[row] = acc;
        }
    }
}

__device__ __forceinline__ unsigned int f2key(float f) {
    unsigned int u = __float_as_uint(f);
    return u ^ ((u >> 31) ? 0xFFFFFFFFu : 0x80000000u);
}

// ======== K2: rank by (s2, idx), one dispatch (R5-proven) ========
__global__ __launch_bounds__(256) void k_rank(const float* __restrict__ s2,
        int* __restrict__ order, float* __restrict__ s2s,
        double* __restrict__ wpos, double* __restrict__ wneg) {
    __shared__ unsigned int sk[NN];   // 32 KB
    __shared__ int2 part[8][32];
    const int tid = threadIdx.x;
    {
        const float4* src = reinterpret_cast<const float4*>(s2);
        #pragma unroll
        for (int t = 0; t < 8; ++t) {
            const float4 v = src[tid + t * 256];
            const int b = (tid + t * 256) * 4;
            sk[b] = f2key(v.x); sk[b+1] = f2key(v.y); sk[b+2] = f2key(v.z); sk[b+3] = f2key(v.w);
        }
    }
    __syncthreads();
    const int jl = tid & 7, seg = tid >> 3;
    const int j0 = blockIdx.x * 16 + jl, j1 = j0 + 8;
    const unsigned int k0 = sk[j0], k1 = sk[j1];
    const int base = seg * 256;
    int c0 = 0, c1 = 0;
    for (int q = 0; q < 64; ++q) {
        const int qq = (q + seg) & 63;
        const int idx = base + qq * 4;
        const uint4 v = *reinterpret_cast<const uint4*>(&sk[idx]);
        c0 += (v.x < k0) | ((v.x == k0) & (idx     < j0));
        c0 += (v.y < k0) | ((v.y == k0) & (idx + 1 < j0));
        c0 += (v.z < k0) | ((v.z == k0) & (idx + 2 < j0));
        c0 += (v.w < k0) | ((v.w == k0) & (idx + 3 < j0));
        c1 += (v.x < k1) | ((v.x == k1) & (idx     < j1));
        c1 += (v.y < k1) | ((v.y == k1) & (idx + 1 < j1));
        c1 += (v.z < k1) | ((v.z == k1) & (idx + 2 < j1));
        c1 += (v.w < k1) | ((v.w == k1) & (idx + 3 < j1));
    }
    part[jl][seg] = make_int2(c0, c1);
    __syncthreads();
    if (tid < 16) {
        const int jloc = tid & 7, hi = tid >> 3;
        int r = 0;
        #pragma unroll
        for (int s = 0; s < 32; ++s) r += hi ? part[jloc][s].y : part[jloc][s].x;
        const int jj = blockIdx.x * 16 + jloc + 8 * hi;
        const float v = s2[jj];
        order[r] = jj;
        s2s[r] = v;
        wpos[r] = exp((double)v);
        wneg[r] = exp(0.2 * (double)v);
    }
}

// col-group helpers (R4-proven): g<8 -> pos h1; g<16 -> neg h1; g==16 -> ones
__device__ __forceinline__ void load_vals(int g, int p, const float* __restrict__ h1,
        const int* __restrict__ order, const double* __restrict__ wpos,
        const double* __restrict__ wneg, double* vals, int& ncols, int& colbase) {
    if (g < 16) {
        ncols = 8;
        const int d0 = (g < 8) ? 8 * g : 8 * (g - 8);
        colbase = (g < 8) ? d0 : 64 + d0;
        const double wgt = (g < 8) ? wpos[p] : wneg[p];
        const float* hp = h1 + (size_t)order[p] * DF + d0;
        const float4 h0 = *reinterpret_cast<const float4*>(hp);
        const float4 h4 = *reinterpret_cast<const float4*>(hp + 4);
        vals[0]=wgt*h0.x; vals[1]=wgt*h0.y; vals[2]=wgt*h0.z; vals[3]=wgt*h0.w;
        vals[4]=wgt*h4.x; vals[5]=wgt*h4.y; vals[6]=wgt*h4.z; vals[7]=wgt*h4.w;
    } else {
        ncols = 2; colbase = 128;
        vals[0] = wpos[p]; vals[1] = wneg[p];
    }
}

// ======== K3: per-(col,chunk) totals (R4-proven) ========
__global__ __launch_bounds__(256) void k_csum(const float* __restrict__ h1,
        const int* __restrict__ order, const double* __restrict__ wpos,
        const double* __restrict__ wneg, double* __restrict__ cT) {
    const int g = blockIdx.x, c = blockIdx.y;
    const int tid = threadIdx.x, lane = tid & 63, w = tid >> 6;
    const int p = c * 256 + tid;
    double vals[8]; int ncols, colbase;
    load_vals(g, p, h1, order, wpos, wneg, vals, ncols, colbase);
    __shared__ double red[4][8];
    for (int jj = 0; jj < ncols; ++jj) {
        double r = vals[jj];
        #pragma unroll
        for (int off = 32; off; off >>= 1) r += __shfl_xor(r, off);
        if (lane == 0) red[w][jj] = r;
    }
    __syncthreads();
    if (tid < ncols)
        cT[(size_t)(colbase + tid) * NCH + c] = red[0][tid] + red[1][tid] + red[2][tid] + red[3][tid];
}

// ======== K4: exclusive scan -> E, cT prefix inlined (R4-proven) ========
__global__ __launch_bounds__(256) void k_scan(const float* __restrict__ h1,
        const int* __restrict__ order, const double* __restrict__ wpos,
        const double* __restrict__ wneg, const double* __restrict__ cT,
        double* __restrict__ E) {
    const int g = blockIdx.x, c = blockIdx.y;
    const int tid = threadIdx.x, lane = tid & 63, w = tid >> 6;
    const int p = c * 256 + tid;
    double vals[8], inc8[8]; int ncols, colbase;
    load_vals(g, p, h1, order, wpos, wneg, vals, ncols, colbase);
    __shared__ double cOs[8];
    __shared__ double wtot[4][8];
    if (tid < ncols) {
        double s = 0.0;
        const double* ct = cT + (size_t)(colbase + tid) * NCH;
        for (int cc = 0; cc < c; ++cc) s += ct[cc];
        cOs[tid] = s;
    }
    for (int jj = 0; jj < ncols; ++jj) {
        double incl = vals[jj];
        #pragma unroll
        for (int off = 1; off < 64; off <<= 1) {
            double t = __shfl_up(incl, off);
            if (lane >= off) incl += t;
        }
        inc8[jj] = incl;
        if (lane == 63) wtot[w][jj] = incl;
    }
    __syncthreads();
    double* Ep = E + (size_t)p * EC + colbase;
    for (int jj = 0; jj < ncols; ++jj) {
        double woff = cOs[jj];
        for (int ww = 0; ww < w; ++ww) woff += wtot[ww][jj];
        Ep[jj] = woff + inc8[jj] - vals[jj];
    }
    if (c == NCH - 1 && tid < ncols)
        E[(size_t)NN * EC + colbase + tid] =
            cOs[tid] + wtot[0][tid] + wtot[1][tid] + wtot[2][tid] + wtot[3][tid];
}

// ======== K5: LDS-staged binary search + combine (R5-proven, s1 from buffer) ========
__global__ __launch_bounds__(256) void k_out(const float* __restrict__ s1,
        const float* __restrict__ s2s, const double* __restrict__ E,
        float* __restrict__ out) {
    __shared__ float ss[NN];   // 32 KB sorted keys
    const int tid = threadIdx.x;
    {
        const float4* src = reinterpret_cast<const float4*>(s2s);
        float4* dst = reinterpret_cast<float4*>(ss);
        #pragma unroll
        for (int t = 0; t < 8; ++t) dst[tid + t * 256] = src[tid + t * 256];
    }
    __syncthreads();
    const int lane = tid & 63, w = tid >> 6;
    const int i0 = blockIdx.x * 16 + w * 4;
    float s1v[4];
    #pragma unroll
    for (int r = 0; r < 4; ++r) s1v[r] = s1[i0 + r];
    int lo[4] = {0, 0, 0, 0}, hi[4] = {NN, NN, NN, NN};
    for (int step = 0; step < 13; ++step) {
        #pragma unroll
        for (int r = 0; r < 4; ++r) {
            const int mid = (lo[r] + hi[r]) >> 1;
            if (ss[mid] < -s1v[r]) lo[r] = mid + 1; else hi[r] = mid;
        }
    }
    const double* Et = E + (size_t)NN * EC;
    #pragma unroll
    for (int r = 0; r < 4; ++r) {
        const double* Ek = E + (size_t)lo[r] * EC;
        const double e1 = exp((double)s1v[r]);
        const double e2 = exp(0.2 * (double)s1v[r]);
        const double num = e1 * (Et[lane] - Ek[lane]) + e2 * Ek[64 + lane];
        const double den = e1 * (Et[128] - Ek[128]) + e2 * Ek[129];
        out[(size_t)(i0 + r) * DF + lane] = (float)(num / den);
    }
}

extern "C" void kernel_launch(void* const* d_in, const int* in_sizes, int n_in,
                              void* d_out, int out_size, void* d_ws, size_t ws_size,
                              hipStream_t stream) {
    const float* x    = (const float*)d_in[0];
    const float* nmat = (const float*)d_in[1];
    const float* W    = (const float*)d_in[2];
    const float* w1   = (const float*)d_in[3];
    const float* w2   = (const float*)d_in[4];
    float* out = (float*)d_out;

    char* ws = (char*)d_ws;
    size_t off = 0;
    auto alloc = [&](size_t bytes) -> void* {
        void* p = ws + off;
        off += (bytes + 255) & ~(size_t)255;
        return p;
    };
    unsigned short* Wh = (unsigned short*)alloc((size_t)DF * KF * 2);   // 64 KB
    unsigned short* Wl = (unsigned short*)alloc((size_t)DF * KF * 2);   // 64 KB
    float*  v2    = (float*)alloc((size_t)KF * 4);
    float*  h1    = (float*)alloc((size_t)NN * DF * 4);                 // 2 MB
    float*  s1    = (float*)alloc((size_t)NN * 4);
    float*  s2    = (float*)alloc((size_t)NN * 4);
    int*    order = (int*)alloc((size_t)NN * 4);
    float*  s2s   = (float*)alloc((size_t)NN * 4);
    double* wpos  = (double*)alloc((size_t)NN * 8);
    double* wneg  = (double*)alloc((size_t)NN * 8);
    double* cT    = (double*)alloc((size_t)130 * NCH * 8);
    double* E     = (double*)alloc((size_t)(NN + 1) * EC * 8);          // 8.9 MB

    k_prep<<<2, 256, 0, stream>>>(W, w2, v2, Wh, Wl);
    k_main<<<768, 256, 0, stream>>>(x, nmat, Wh, Wl, v2, w1, h1, s1, s2);
    k_rank<<<512, 256, 0, stream>>>(s2, order, s2s, wpos, wneg);
    k_csum<<<dim3(17, NCH), 256, 0, stream>>>(h1, order, wpos, wneg, cT);
    k_scan<<<dim3(17, NCH), 256, 0, stream>>>(h1, order, wpos, wneg, cT, E);
    k_out<<<NN / 16, 256, 0, stream>>>(s1, s2s, E, out);
}